// Round 5
// baseline (147.046 us; speedup 1.0000x reference)
//
#include <hip/hip_runtime.h>
#include <hip/hip_bf16.h>

// Problem constants
#define BATCH 8
#define CDIM 256     // QDIM == KDIM
#define SEQ 1024     // 32*32
#define EMB 512
#define NHEAD 8
#define HDIM 64

typedef __bf16 bf16x8 __attribute__((ext_vector_type(8)));
typedef float f32x4 __attribute__((ext_vector_type(4)));
typedef float f32x16 __attribute__((ext_vector_type(16)));

static __device__ __forceinline__ unsigned short f2b(float f) {
    __hip_bfloat16 h = __float2bfloat16(f);
    return __builtin_bit_cast(unsigned short, h);
}

static __device__ __forceinline__ f32x4 mfma16(bf16x8 a, bf16x8 b, f32x4 c) {
    return __builtin_amdgcn_mfma_f32_16x16x32_bf16(a, b, c, 0, 0, 0);
}
static __device__ __forceinline__ f32x16 mfma32(bf16x8 a, bf16x8 b, f32x16 c) {
    return __builtin_amdgcn_mfma_f32_32x32x16_bf16(a, b, c, 0, 0, 0);
}

// async global->LDS, 16B per lane; LDS dest is wave-uniform base + lane*16
static __device__ __forceinline__ void gload16(const void* g, void* l) {
    __builtin_amdgcn_global_load_lds(
        (const __attribute__((address_space(1))) unsigned int*)g,
        (__attribute__((address_space(3))) unsigned int*)l, 16, 0, 0);
}

// ---------------------------------------------------------------------------
// Kernel 1: prep. z<16: (B,C,S) f32 -> (B,S,C) bf16 transpose+convert with
// T2 XOR-swizzle baked into the global layout (col^=((row&7)<<3) shorts).
// z>=16: W f32 -> Wc bf16, same swizzle. Consumers: proj only (reads with
// matching XOR after linear global_load_lds staging).
// grid (16, 4, 19), block 256
// ---------------------------------------------------------------------------
__global__ __launch_bounds__(256) void prep_kernel(
    const float* __restrict__ query, const float* __restrict__ key_,
    const float* __restrict__ Wq, const float* __restrict__ Wk,
    const float* __restrict__ Wv,
    unsigned short* __restrict__ Xq, unsigned short* __restrict__ Xk,
    unsigned short* __restrict__ Wc)
{
    int tid = threadIdx.x;
    int z = blockIdx.z;
    if (z >= 16) {  // W conversion path
        int pz = z - 16;
        const float* W = (pz == 0) ? Wq : (pz == 1 ? Wk : Wv);
        int lin = blockIdx.y * 16 + blockIdx.x;
        int idx = (lin * 256 + tid) * 8;       // elem within 512x256
        int e7 = (idx >> 8) & 7;               // row & 7
        float4 v0 = *(const float4*)&W[idx];
        float4 v1 = *(const float4*)&W[idx + 4];
        int4 pk;
        pk.x = (int)((unsigned)f2b(v0.x) | ((unsigned)f2b(v0.y) << 16));
        pk.y = (int)((unsigned)f2b(v0.z) | ((unsigned)f2b(v0.w) << 16));
        pk.z = (int)((unsigned)f2b(v1.x) | ((unsigned)f2b(v1.y) << 16));
        pk.w = (int)((unsigned)f2b(v1.z) | ((unsigned)f2b(v1.w) << 16));
        int dsti = (idx & ~255) | ((idx & 255) ^ (e7 << 3));  // swizzled col
        *(int4*)&Wc[(size_t)pz * (EMB * CDIM) + dsti] = pk;
        return;
    }
    __shared__ alignas(16) unsigned short sT[64 * 66];
    int s0 = blockIdx.x * 64, c0 = blockIdx.y * 64;
    int which = z >> 3, b = z & 7;
    const float* src = which ? key_ : query;
    unsigned short* dst = which ? Xk : Xq;

#pragma unroll
    for (int p = 0; p < 4; ++p) {
        int c = (tid >> 4) + p * 16;
        int sch = tid & 15;
        float4 v = *(const float4*)&src[((size_t)b * CDIM + c0 + c) * SEQ + s0 + sch * 4];
        sT[c * 66 + sch * 4 + 0] = f2b(v.x);
        sT[c * 66 + sch * 4 + 1] = f2b(v.y);
        sT[c * 66 + sch * 4 + 2] = f2b(v.z);
        sT[c * 66 + sch * 4 + 3] = f2b(v.w);
    }
    __syncthreads();
#pragma unroll
    for (int p = 0; p < 4; ++p) {
        int s = (tid >> 4) + p * 16;
        int cch = tid & 15;
        unsigned short e0 = sT[(cch * 4 + 0) * 66 + s];
        unsigned short e1 = sT[(cch * 4 + 1) * 66 + s];
        unsigned short e2 = sT[(cch * 4 + 2) * 66 + s];
        unsigned short e3 = sT[(cch * 4 + 3) * 66 + s];
        uint2 pk;
        pk.x = (unsigned)e0 | ((unsigned)e1 << 16);
        pk.y = (unsigned)e2 | ((unsigned)e3 << 16);
        int col = (cch * 4) ^ ((s & 7) << 3);  // pre-swizzle (row = s0+s, s0%64==0)
        *(uint2*)&dst[((size_t)b * SEQ + s0 + s) * CDIM + c0 + col] = pk;
    }
}

// ---------------------------------------------------------------------------
// Kernel 2: fused projection GEMM over M = B*S = 8192, N = 1536 (Wq|Wk|Wv).
// BM=128 BN=128 BK=64, 4 waves (2x2), wave tile 64x64, 16x16x32 MFMA.
// Staging: global_load_lds dwordx4 into UNPADDED [128][64] LDS; inputs are
// pre-swizzled in global (col^((row&7)<<3)), fragment reads apply same XOR
// -> 2-way (free) bank aliasing instead of 16-way.
// Operand order per projection -> packed 8B epilogue stores (r3).
// grid (12, 64), block 256
// ---------------------------------------------------------------------------
__global__ __launch_bounds__(256) void proj_kernel(
    const unsigned short* __restrict__ Xq, const unsigned short* __restrict__ Xk,
    const unsigned short* __restrict__ Wc,
    const float* __restrict__ bq, const float* __restrict__ bk,
    const float* __restrict__ bv,
    unsigned short* __restrict__ Qb, unsigned short* __restrict__ Kb,
    unsigned short* __restrict__ Vt)
{
    __shared__ alignas(16) unsigned short sX[128 * 64];
    __shared__ alignas(16) unsigned short sW[128 * 64];
    int tid = threadIdx.x;
    int n0 = blockIdx.x * 128;
    int m0 = blockIdx.y * 128;
    int proj = n0 >> 9;
    const unsigned short* X = (proj == 0) ? Xq : Xk;
    const float* bias = (proj == 0) ? bq : (proj == 1 ? bk : bv);

    int lane = tid & 63, w = tid >> 6;
    int l16 = lane & 15, lhi = lane >> 4;
    int wr = w >> 1, wc = w & 1;
    int lrow = lane >> 3, lcb = (lane & 7) * 8;  // staging: 8 lanes per 64-short row

    f32x4 zero = {0.f, 0.f, 0.f, 0.f};
    f32x4 acc[4][4];
#pragma unroll
    for (int i = 0; i < 4; ++i)
#pragma unroll
        for (int j = 0; j < 4; ++j) acc[i][j] = zero;

    for (int kt = 0; kt < 4; ++kt) {
        int c0 = kt * 64;
        if (kt) __syncthreads();
#pragma unroll
        for (int i = 0; i < 4; ++i) {
            int seg = i * 4 + w;            // 16 segments of 8 rows
            int row = seg * 8 + lrow;
            gload16(&X[(size_t)(m0 + row) * CDIM + c0 + lcb], &sX[seg * 512]);
            gload16(&Wc[(size_t)(n0 + row) * CDIM + c0 + lcb], &sW[seg * 512]);
        }
        __syncthreads();  // compiler inserts vmcnt(0) before barrier
        const unsigned short* tA = (proj == 2) ? &sX[0] : &sW[0];
        const unsigned short* tB = (proj == 2) ? &sW[0] : &sX[0];
#pragma unroll
        for (int kk = 0; kk < 2; ++kk) {
            bf16x8 af[4], bfr[4];
#pragma unroll
            for (int i = 0; i < 4; ++i) {
                int r = wr * 64 + i * 16 + l16;
                af[i] = *(const bf16x8*)&tA[r * 64 + ((kk * 32 + lhi * 8) ^ ((r & 7) << 3))];
            }
#pragma unroll
            for (int j = 0; j < 4; ++j) {
                int r = wc * 64 + j * 16 + l16;
                bfr[j] = *(const bf16x8*)&tB[r * 64 + ((kk * 32 + lhi * 8) ^ ((r & 7) << 3))];
            }
#pragma unroll
            for (int i = 0; i < 4; ++i)
#pragma unroll
                for (int j = 0; j < 4; ++j)
                    acc[i][j] = mfma16(af[i], bfr[j], acc[i][j]);
        }
    }

    if (proj != 2) {
        // swapped: e = (n0&511)+wr*64+i*16+lhi*4+r ; s = m0+wc*64+j*16+l16
        unsigned short* dst = proj ? Kb : Qb;
        float scale = proj ? 1.0f : (0.125f * 1.44269504f);  // Q: /sqrt(64)*log2e
#pragma unroll
        for (int i = 0; i < 4; ++i) {
            int e0 = (n0 & 511) + wr * 64 + i * 16 + lhi * 4;
            float4 bv4 = *(const float4*)&bias[e0];
            int hh = e0 >> 6, dd = e0 & 63;
#pragma unroll
            for (int j = 0; j < 4; ++j) {
                int mg = m0 + wc * 64 + j * 16 + l16;
                int bb = mg >> 10, s = mg & 1023;
                uint2 pk;
                pk.x = (unsigned)f2b((acc[i][j][0] + bv4.x) * scale) |
                       ((unsigned)f2b((acc[i][j][1] + bv4.y) * scale) << 16);
                pk.y = (unsigned)f2b((acc[i][j][2] + bv4.z) * scale) |
                       ((unsigned)f2b((acc[i][j][3] + bv4.w) * scale) << 16);
                *(uint2*)&dst[(((size_t)bb * NHEAD + hh) * SEQ + s) * HDIM + dd] = pk;
            }
        }
    } else {
        // unswapped: s = m0+wr*64+i*16+lhi*4+r ; e = (n0&511)+wc*64+j*16+l16
#pragma unroll
        for (int j = 0; j < 4; ++j) {
            int e = (n0 & 511) + wc * 64 + j * 16 + l16;
            float bval = bias[e];
            int hh = e >> 6, dd = e & 63;
#pragma unroll
            for (int i = 0; i < 4; ++i) {
                int mg = m0 + wr * 64 + i * 16 + lhi * 4;
                int bb = mg >> 10, s = mg & 1023;
                uint2 pk;
                pk.x = (unsigned)f2b(acc[i][j][0] + bval) |
                       ((unsigned)f2b(acc[i][j][1] + bval) << 16);
                pk.y = (unsigned)f2b(acc[i][j][2] + bval) |
                       ((unsigned)f2b(acc[i][j][3] + bval) << 16);
                *(uint2*)&Vt[(((size_t)bb * NHEAD + hh) * HDIM + dd) * SEQ + s] = pk;
            }
        }
    }
}

// ---------------------------------------------------------------------------
// Kernel 3: causal flash attention. 1 wave per block, 32 q-rows per wave.
// KV tile = 64 (halves per-tile fixed softmax/loop overhead, doubles MFMA
// cluster size) + s_setprio(1) around MFMA clusters (T5).
// Swapped QK^T (mfma(K,Q) -> S^T), in-register softmax, cvt_pk+permlane32
// P repack, no LDS/barriers. K 2-deep buffered, V just-in-time.
// grid (B*H=64, S/32=32): head pinned to one XCD; longest blocks first.
// ---------------------------------------------------------------------------
__global__ __launch_bounds__(64, 2) void attn_kernel(
    const unsigned short* __restrict__ Qb, const unsigned short* __restrict__ Kb,
    const unsigned short* __restrict__ Vt, float* __restrict__ out)
{
    int lane = threadIdx.x;
    int l32 = lane & 31, hi = lane >> 5;
    int bh = blockIdx.x;
    int qt = (int)(gridDim.y - 1 - blockIdx.y);
    int b = bh >> 3, h = bh & 7;
    int q0 = qt * 32;

    const unsigned short* Qhead = Qb + (size_t)bh * SEQ * HDIM;
    const unsigned short* Khead = Kb + (size_t)bh * SEQ * HDIM;
    const unsigned short* Vhead = Vt + (size_t)bh * HDIM * SEQ;

    bf16x8 qf[4];
#pragma unroll
    for (int dblk = 0; dblk < 4; ++dblk)
        qf[dblk] = *(const bf16x8*)&Qhead[(size_t)(q0 + l32) * HDIM + dblk * 16 + hi * 8];

    f32x16 o0, o1;
#pragma unroll
    for (int r = 0; r < 16; ++r) { o0[r] = 0.f; o1[r] = 0.f; }
    float m = -1e30f, l = 0.f;

    bf16x8 kA[8], kB[8], vv[8], vtl[4];

    auto loadK64 = [&](int k0, bf16x8 (&ka)[8]) {
#pragma unroll
        for (int h2 = 0; h2 < 2; ++h2)
#pragma unroll
            for (int dblk = 0; dblk < 4; ++dblk)
                ka[h2 * 4 + dblk] = *(const bf16x8*)
                    &Khead[(size_t)(k0 + h2 * 32 + l32) * HDIM + dblk * 16 + hi * 8];
    };
    auto loadK32 = [&](int k0, bf16x8 (&ka)[8]) {
#pragma unroll
        for (int dblk = 0; dblk < 4; ++dblk)
            ka[dblk] = *(const bf16x8*)&Khead[(size_t)(k0 + l32) * HDIM + dblk * 16 + hi * 8];
    };
    auto loadV64 = [&](int k0) {
#pragma unroll
        for (int t2 = 0; t2 < 2; ++t2)
#pragma unroll
            for (int ks = 0; ks < 4; ++ks)
                vv[t2 * 4 + ks] = *(const bf16x8*)
                    &Vhead[(size_t)(t2 * 32 + l32) * SEQ + k0 + ks * 16 + hi * 8];
    };
    auto loadV32 = [&](int k0) {
#pragma unroll
        for (int t2 = 0; t2 < 2; ++t2)
#pragma unroll
            for (int ks = 0; ks < 2; ++ks)
                vtl[t2 * 2 + ks] = *(const bf16x8*)
                    &Vhead[(size_t)(t2 * 32 + l32) * SEQ + k0 + ks * 16 + hi * 8];
    };
    auto packP = [&](const f32x16& st, bf16x8& pbA, bf16x8& pbB) {
        unsigned u[8];
#pragma unroll
        for (int i = 0; i < 8; ++i) {
            unsigned r_;
            asm("v_cvt_pk_bf16_f32 %0, %1, %2" : "=v"(r_) : "v"(st[2 * i]), "v"(st[2 * i + 1]));
            u[i] = r_;
        }
        asm("v_permlane32_swap_b32 %0, %1" : "+v"(u[0]), "+v"(u[2]));
        asm("v_permlane32_swap_b32 %0, %1" : "+v"(u[1]), "+v"(u[3]));
        asm("v_permlane32_swap_b32 %0, %1" : "+v"(u[4]), "+v"(u[6]));
        asm("v_permlane32_swap_b32 %0, %1" : "+v"(u[5]), "+v"(u[7]));
        uint4 w0 = {u[0], u[1], u[2], u[3]};
        uint4 w1 = {u[4], u[5], u[6], u[7]};
        pbA = __builtin_bit_cast(bf16x8, w0);
        pbB = __builtin_bit_cast(bf16x8, w1);
    };

    auto tile64 = [&](const bf16x8 (&ka)[8], bool maskDiag) {
        f32x16 st0, st1;
#pragma unroll
        for (int r = 0; r < 16; ++r) { st0[r] = 0.f; st1[r] = 0.f; }
        __builtin_amdgcn_s_setprio(1);
#pragma unroll
        for (int dblk = 0; dblk < 4; ++dblk) st0 = mfma32(ka[dblk], qf[dblk], st0);
#pragma unroll
        for (int dblk = 0; dblk < 4; ++dblk) st1 = mfma32(ka[4 + dblk], qf[dblk], st1);
        __builtin_amdgcn_s_setprio(0);
        if (maskDiag) {  // st1 keys = q0 + cd
#pragma unroll
            for (int r = 0; r < 16; ++r) {
                int cd = (r & 3) + 8 * (r >> 2) + 4 * hi;
                if (cd > l32) st1[r] = -1e38f;
            }
        }
        float t16[16];
#pragma unroll
        for (int r = 0; r < 16; ++r) t16[r] = fmaxf(st0[r], st1[r]);
        float t8[8];
#pragma unroll
        for (int r = 0; r < 8; ++r) t8[r] = fmaxf(t16[r], t16[r + 8]);
        float t4[4];
#pragma unroll
        for (int r = 0; r < 4; ++r) t4[r] = fmaxf(t8[r], t8[r + 4]);
        float tmax = fmaxf(fmaxf(t4[0], t4[2]), fmaxf(t4[1], t4[3]));
        tmax = fmaxf(tmax, __shfl_xor(tmax, 32));
        if (!__all(tmax <= m + 8.0f)) {  // defer-max, exp2 domain
            float mnew = fmaxf(m, tmax);
            float corr = __builtin_amdgcn_exp2f(m - mnew);
#pragma unroll
            for (int r = 0; r < 16; ++r) { o0[r] *= corr; o1[r] *= corr; }
            l *= corr;
            m = mnew;
        }
#pragma unroll
        for (int r = 0; r < 16; ++r) {
            st0[r] = __builtin_amdgcn_exp2f(st0[r] - m);
            st1[r] = __builtin_amdgcn_exp2f(st1[r] - m);
        }
        float s16[16];
#pragma unroll
        for (int r = 0; r < 16; ++r) s16[r] = st0[r] + st1[r];
        float s8[8];
#pragma unroll
        for (int r = 0; r < 8; ++r) s8[r] = s16[r] + s16[r + 8];
        float s4[4];
#pragma unroll
        for (int r = 0; r < 4; ++r) s4[r] = s8[r] + s8[r + 4];
        float ts = (s4[0] + s4[2]) + (s4[1] + s4[3]);
        ts += __shfl_xor(ts, 32);
        l += ts;
        bf16x8 pb0, pb1, pb2, pb3;
        packP(st0, pb0, pb1);
        packP(st1, pb2, pb3);
        __builtin_amdgcn_s_setprio(1);
        o0 = mfma32(vv[0], pb0, o0); o1 = mfma32(vv[4], pb0, o1);
        o0 = mfma32(vv[1], pb1, o0); o1 = mfma32(vv[5], pb1, o1);
        o0 = mfma32(vv[2], pb2, o0); o1 = mfma32(vv[6], pb2, o1);
        o0 = mfma32(vv[3], pb3, o0); o1 = mfma32(vv[7], pb3, o1);
        __builtin_amdgcn_s_setprio(0);
    };

    auto tile32 = [&](const bf16x8 (&ka)[8]) {  // diagonal 32-wide tile at q0
        f32x16 st0;
#pragma unroll
        for (int r = 0; r < 16; ++r) st0[r] = 0.f;
        __builtin_amdgcn_s_setprio(1);
#pragma unroll
        for (int dblk = 0; dblk < 4; ++dblk) st0 = mfma32(ka[dblk], qf[dblk], st0);
        __builtin_amdgcn_s_setprio(0);
#pragma unroll
        for (int r = 0; r < 16; ++r) {
            int cd = (r & 3) + 8 * (r >> 2) + 4 * hi;
            if (cd > l32) st0[r] = -1e38f;
        }
        float t8[8];
#pragma unroll
        for (int r = 0; r < 8; ++r) t8[r] = fmaxf(st0[r], st0[r + 8]);
        float t4[4];
#pragma unroll
        for (int r = 0; r < 4; ++r) t4[r] = fmaxf(t8[r], t8[r + 4]);
        float tmax = fmaxf(fmaxf(t4[0], t4[2]), fmaxf(t4[1], t4[3]));
        tmax = fmaxf(tmax, __shfl_xor(tmax, 32));
        if (!__all(tmax <= m + 8.0f)) {
            float mnew = fmaxf(m, tmax);
            float corr = __builtin_amdgcn_exp2f(m - mnew);
#pragma unroll
            for (int r = 0; r < 16; ++r) { o0[r] *= corr; o1[r] *= corr; }
            l *= corr;
            m = mnew;
        }
#pragma unroll
        for (int r = 0; r < 16; ++r) st0[r] = __builtin_amdgcn_exp2f(st0[r] - m);
        float s8[8];
#pragma unroll
        for (int r = 0; r < 8; ++r) s8[r] = st0[r] + st0[r + 8];
        float s4[4];
#pragma unroll
        for (int r = 0; r < 4; ++r) s4[r] = s8[r] + s8[r + 4];
        float ts = (s4[0] + s4[2]) + (s4[1] + s4[3]);
        ts += __shfl_xor(ts, 32);
        l += ts;
        bf16x8 pb0, pb1;
        packP(st0, pb0, pb1);
        __builtin_amdgcn_s_setprio(1);
        o0 = mfma32(vtl[0], pb0, o0); o0 = mfma32(vtl[1], pb1, o0);
        o1 = mfma32(vtl[2], pb0, o1); o1 = mfma32(vtl[3], pb1, o1);
        __builtin_amdgcn_s_setprio(0);
    };

    int nt64 = (qt + 1) >> 1;
    bool tail = ((qt & 1) == 0);  // diagonal handled by a 32-tile when qt even

    if (nt64 == 0) {
        loadK32(0, kA);
        loadV32(0);
        tile32(kA);
    } else {
        loadK64(0, kA);
        int t = 0;
        while (true) {
            loadV64(t * 64);
            if (t + 1 < nt64) loadK64((t + 1) * 64, kB);
            else if (tail) { loadK32(q0, kB); loadV32(q0); }
            tile64(kA, (t == nt64 - 1) && !tail);
            if (++t >= nt64) { if (tail) tile32(kB); break; }
            loadV64(t * 64);
            if (t + 1 < nt64) loadK64((t + 1) * 64, kA);
            else if (tail) { loadK32(q0, kA); loadV32(q0); }
            tile64(kB, (t == nt64 - 1) && !tail);
            if (++t >= nt64) { if (tail) tile32(kA); break; }
        }
    }

    float inv = 1.0f / l;
    size_t base = ((size_t)b * EMB + h * HDIM) * SEQ + q0 + l32;
#pragma unroll
    for (int r = 0; r < 16; ++r) {
        int d0 = (r & 3) + 8 * (r >> 2) + 4 * hi;
        out[base + (size_t)d0 * SEQ] = o0[r] * inv;
        out[base + (size_t)(d0 + 32) * SEQ] = o1[r] * inv;
    }
}

// ---------------------------------------------------------------------------
extern "C" void kernel_launch(void* const* d_in, const int* in_sizes, int n_in,
                              void* d_out, int out_size, void* d_ws, size_t ws_size,
                              hipStream_t stream) {
    const float* query = (const float*)d_in[0];
    const float* key_  = (const float*)d_in[1];
    const float* Wq    = (const float*)d_in[2];
    const float* bq    = (const float*)d_in[3];
    const float* Wk    = (const float*)d_in[4];
    const float* bk    = (const float*)d_in[5];
    const float* Wv    = (const float*)d_in[6];
    const float* bv    = (const float*)d_in[7];
    float* out = (float*)d_out;

    char* ws = (char*)d_ws;
    unsigned short* Qb = (unsigned short*)(ws);                    // 8 MiB (B,H,S,D)
    unsigned short* Kb = (unsigned short*)(ws + 8388608);          // 8 MiB (B,H,S,D)
    unsigned short* Vt = (unsigned short*)(ws + 16777216);         // 8 MiB (B,H,D,S)
    unsigned short* Xq = (unsigned short*)(ws + 25165824);         // 4 MiB (B,S,C) swz
    unsigned short* Xk = (unsigned short*)(ws + 29360128);         // 4 MiB (B,S,C) swz
    // Wc (1536x256 bf16 swizzled, 768 KiB) in the tail of d_out; attn
    // overwrites all of d_out afterwards (stream-ordered) -> free scratch.
    unsigned short* Wc = (unsigned short*)((char*)d_out + 16777216 - 1048576);

    prep_kernel<<<dim3(16, 4, 19), 256, 0, stream>>>(query, key_, Wq, Wk, Wv, Xq, Xk, Wc);
    proj_kernel<<<dim3(12, 64), 256, 0, stream>>>(Xq, Xk, Wc, bq, bk, bv, Qb, Kb, Vt);
    attn_kernel<<<dim3(BATCH * NHEAD, SEQ / 32), 64, 0, stream>>>(Qb, Kb, Vt, out);
}